// Round 1
// baseline (862.315 us; speedup 1.0000x reference)
//
#include <hip/hip_runtime.h>
#include <math.h>

// ---- problem constants ----
#define T_TOK   16384
#define DMODEL  1024
#define DFF     4096
#define NEXP    8
#define CAPACITY 3277            // ceil(16384*1.6/8)
#define CAP_PAD  3328            // ceil(CAPACITY/128)*128
#define MAXR    (T_TOK + NEXP*128)   // 17408: max total padded rows across experts

typedef unsigned short u16;
typedef __attribute__((ext_vector_type(8))) __bf16 bf16x8;
typedef __attribute__((ext_vector_type(4))) float  f32x4;

// ---- workspace layout (bytes). Total ~299 MB. ----
#define W1T_OFF   0ull                         // 8*4096*1024*2 = 67108864   bf16 [E][DFF][D]  (B^T for GEMM1)
#define W2T_OFF   67108864ull                  // 67108864                   bf16 [E][D][DFF]  (B^T for GEMM2)
#define XG_OFF    134217728ull                 // 17408*1024*2 = 35651584    bf16 gathered x rows
#define H_OFF     169869312ull                 // 17408*4096*2 = 142606336   bf16 hidden
#define TOPK_OFF  312475648ull                 // 16384*2*4 = 131072
#define CCNT_OFF  312606720ull                 // 128*8*4
#define CBASE_OFF 312610816ull                 // 128*8*4
#define LISTS_OFF 312614912ull                 // 8*3328*4 = 106496
#define CNT_OFF   312721408ull                 // 8*4
#define OFFS_OFF  312721472ull                 // 9*4
#define PCNT_OFF  312721536ull                 // 8*4

__device__ __forceinline__ u16 f2bf(float x) {   // round-to-nearest-even f32->bf16
  union { float f; unsigned u; } v; v.f = x;
  unsigned r = v.u + 0x7fffu + ((v.u >> 16) & 1u);
  return (u16)(r >> 16);
}

__device__ __forceinline__ void async_cp16(const void* g, void* l) {
  // global -> LDS direct, 16B/lane. LDS dest is wave-uniform base + lane*16.
  __builtin_amdgcn_global_load_lds((const __attribute__((address_space(1))) void*)g,
                                   (__attribute__((address_space(3))) void*)l,
                                   16, 0, 0);
}

// ---- K1: fp32->bf16 transpose-convert.  src [E][R][C] f32 -> dst [E][C][R] bf16 ----
__global__ __launch_bounds__(256) void transpose_cvt(const float* __restrict__ src,
                                                     u16* __restrict__ dst, int R, int C) {
  int tilesC = C >> 5;
  int per_e = (R >> 5) * tilesC;
  int bid = blockIdx.x;
  int e = bid / per_e, rem = bid % per_e;
  int rt = rem / tilesC, ct = rem % tilesC;
  const float* s = src + (size_t)e * R * C;
  u16* d = dst + (size_t)e * R * C;
  __shared__ float tile[32][33];
  int tx = threadIdx.x & 31, ty = threadIdx.x >> 5;   // 32 x 8
#pragma unroll
  for (int i = 0; i < 4; ++i) {
    int r = rt*32 + ty + i*8;
    tile[ty + i*8][tx] = s[(size_t)r * C + ct*32 + tx];
  }
  __syncthreads();
#pragma unroll
  for (int i = 0; i < 4; ++i) {
    int c = ct*32 + ty + i*8;
    d[(size_t)c * R + rt*32 + tx] = f2bf(tile[tx][ty + i*8]);
  }
}

// ---- K2: router logits + noise, top-2 (fp64 accum to avoid near-tie flips) ----
__global__ __launch_bounds__(256) void router_topk(const float* __restrict__ x,
    const float* __restrict__ rw, const float* __restrict__ rb,
    const float* __restrict__ noise, int* __restrict__ topk) {
  int w = threadIdx.x >> 6, lane = threadIdx.x & 63;
  int t = blockIdx.x * 4 + w;
  const float* xr = x + (size_t)t * DMODEL;
  double acc[NEXP];
#pragma unroll
  for (int e = 0; e < NEXP; ++e) acc[e] = 0.0;
  for (int c = lane; c < DMODEL; c += 64) {
    float xv = xr[c];
#pragma unroll
    for (int e = 0; e < NEXP; ++e) acc[e] += (double)xv * (double)rw[e*DMODEL + c];
  }
#pragma unroll
  for (int e = 0; e < NEXP; ++e) {
#pragma unroll
    for (int off = 32; off > 0; off >>= 1) acc[e] += __shfl_down(acc[e], off, 64);
  }
  if (lane == 0) {
    double best = -1e300, sec = -1e300; int bi = 0, si = 0;
#pragma unroll
    for (int e = 0; e < NEXP; ++e) {
      double v = acc[e] + (double)rb[e] + (double)noise[(size_t)t*NEXP + e] * 0.02;
      if (v > best)     { sec = best; si = bi; best = v; bi = e; }
      else if (v > sec) { sec = v; si = e; }
    }
    topk[2*t] = bi; topk[2*t+1] = si;
  }
}

// ---- K3: per-128-token-chunk routed counts per expert ----
__global__ __launch_bounds__(128) void chunk_count(const int* __restrict__ topk,
                                                   int* __restrict__ ccnt) {
  int tid = threadIdx.x, lane = tid & 63, w = tid >> 6;
  int t = blockIdx.x*128 + tid;
  int i0 = topk[2*t], i1 = topk[2*t+1];
  __shared__ int cnt[2][NEXP];
#pragma unroll
  for (int e = 0; e < NEXP; ++e) {
    unsigned long long bal = __ballot((i0 == e) || (i1 == e));
    if (lane == 0) cnt[w][e] = __popcll(bal);
  }
  __syncthreads();
  if (tid < NEXP) ccnt[blockIdx.x*NEXP + tid] = cnt[0][tid] + cnt[1][tid];
}

// ---- K4: exclusive prefix of chunk counts (tiny) ----
__global__ void chunk_prefix(const int* __restrict__ ccnt, int* __restrict__ cbase) {
  int e = threadIdx.x;
  if (e < NEXP) {
    int run = 0;
    for (int c = 0; c < 128; ++c) { cbase[c*NEXP + e] = run; run += ccnt[c*NEXP + e]; }
  }
}

// ---- K5: capacity acceptance, final expert = max accepted, atomic compaction ----
__global__ __launch_bounds__(128) void assign_compact(const int* __restrict__ topk,
    const int* __restrict__ cbase, int* __restrict__ counts, int* __restrict__ lists) {
  int chunk = blockIdx.x, tid = threadIdx.x;
  int lane = tid & 63, w = tid >> 6;
  int t = chunk*128 + tid;
  int i0 = topk[2*t], i1 = topk[2*t+1];
  __shared__ int w0cnt[NEXP];
  unsigned long long below = (1ull << lane) - 1ull;   // lane 63: 0x7fff... (correct)
#pragma unroll
  for (int e = 0; e < NEXP; ++e) {
    unsigned long long bal = __ballot((i0 == e) || (i1 == e));
    if (w == 0 && lane == 0) w0cnt[e] = __popcll(bal);
  }
  __syncthreads();
  int fin = -1;
#pragma unroll
  for (int e = 0; e < NEXP; ++e) {
    bool m = (i0 == e) || (i1 == e);
    unsigned long long bal = __ballot(m);
    int rank = cbase[chunk*NEXP + e] + (w ? w0cnt[e] : 0) + __popcll(bal & below);
    if (m && rank < CAPACITY) fin = e;    // ascending e -> ends at max accepted
  }
#pragma unroll
  for (int e = 0; e < NEXP; ++e) {
    bool m = (fin == e);
    unsigned long long bal = __ballot(m);
    int c = __popcll(bal);
    if (c) {
      int leader = __ffsll((unsigned long long)bal) - 1;
      int base = 0;
      if (lane == leader) base = atomicAdd(&counts[e], c);
      base = __shfl(base, leader, 64);
      if (m) lists[e*CAP_PAD + base + __popcll(bal & below)] = t;
    }
  }
}

// ---- K6: padded counts + compact region offsets ----
__global__ void calc_offsets(const int* __restrict__ counts, int* __restrict__ offs,
                             int* __restrict__ pcnt) {
  if (threadIdx.x == 0) {
    int run = 0;
    for (int e = 0; e < NEXP; ++e) {
      offs[e] = run;
      int pc = ((counts[e] + 127) >> 7) << 7;
      pcnt[e] = pc;
      run += pc;
    }
    offs[NEXP] = run;
  }
}

// ---- K7: gather x rows -> bf16 compact per-expert regions (pad rows zeroed) ----
__global__ __launch_bounds__(128) void gather_x(const float* __restrict__ x,
    const int* __restrict__ lists, const int* __restrict__ counts,
    const int* __restrict__ offs, const int* __restrict__ pcnt, u16* __restrict__ xg) {
  int bid = blockIdx.x;
  int e = bid / CAP_PAD, r = bid % CAP_PAD;
  if (r >= pcnt[e]) return;
  unsigned long long* dst = (unsigned long long*)(xg + (size_t)(offs[e] + r) * DMODEL);
  int tid = threadIdx.x;
  if (r < counts[e]) {
    const float4* src = (const float4*)(x + (size_t)lists[e*CAP_PAD + r] * DMODEL);
#pragma unroll
    for (int i = 0; i < 2; ++i) {
      float4 v = src[tid + i*128];
      unsigned long long pk = (unsigned long long)f2bf(v.x)
                            | ((unsigned long long)f2bf(v.y) << 16)
                            | ((unsigned long long)f2bf(v.z) << 32)
                            | ((unsigned long long)f2bf(v.w) << 48);
      dst[tid + i*128] = pk;
    }
  } else {
#pragma unroll
    for (int i = 0; i < 2; ++i) dst[tid + i*128] = 0ull;
  }
}

// ---- K8: GEMM1  h = gelu(xg @ w1 + b1), bf16 out. m97 ladder structure. ----
__global__ __launch_bounds__(256) void ffn1_gemm(const u16* __restrict__ xg,
    const u16* __restrict__ w1t, const float* __restrict__ b1,
    const int* __restrict__ offs, const int* __restrict__ pcnt, u16* __restrict__ h) {
  const int BPE = 26*32;
  int bid = blockIdx.x;
  int e = bid / BPE, rem = bid % BPE;
  int mt = rem >> 5, nt = rem & 31;
  if (mt*128 >= pcnt[e]) return;
  const u16* A = xg + (size_t)offs[e] * DMODEL;          // [rows][1024]
  const u16* B = w1t + (size_t)e * DFF * DMODEL;         // [4096][1024] = B^T
  u16* H = h + (size_t)offs[e] * DFF;
  __shared__ __align__(16) u16 As[128*32];
  __shared__ __align__(16) u16 Bs[128*32];
  int tid = threadIdx.x, lane = tid & 63, w = tid >> 6;
  int m0 = mt*128, n0 = nt*128;
  int wm = (w & 1)*64, wn = (w >> 1)*64;
  int fr = lane & 15, fkb = (lane >> 4)*8;
  f32x4 acc[4][4] = {};
  for (int kt = 0; kt < DMODEL; kt += 32) {
    __syncthreads();
#pragma unroll
    for (int i = 0; i < 2; ++i) {
      int slot = i*256 + tid;
      int row = slot >> 2, kc = slot & 3;
      async_cp16(A + (size_t)(m0+row)*DMODEL + kt + kc*8, As + (size_t)(i*256 + w*64)*8);
      async_cp16(B + (size_t)(n0+row)*DMODEL + kt + kc*8, Bs + (size_t)(i*256 + w*64)*8);
    }
    __syncthreads();
    bf16x8 af[4], bf[4];
#pragma unroll
    for (int i = 0; i < 4; ++i) af[i] = *(const bf16x8*)(As + (wm + i*16 + fr)*32 + fkb);
#pragma unroll
    for (int j = 0; j < 4; ++j) bf[j] = *(const bf16x8*)(Bs + (wn + j*16 + fr)*32 + fkb);
#pragma unroll
    for (int i = 0; i < 4; ++i)
#pragma unroll
      for (int j = 0; j < 4; ++j)
        acc[i][j] = __builtin_amdgcn_mfma_f32_16x16x32_bf16(af[i], bf[j], acc[i][j], 0, 0, 0);
  }
  const float* b1e = b1 + e*DFF;
#pragma unroll
  for (int j = 0; j < 4; ++j) {
    int col = n0 + wn + j*16 + (lane & 15);
    float bias = b1e[col];
#pragma unroll
    for (int i = 0; i < 4; ++i) {
#pragma unroll
      for (int r = 0; r < 4; ++r) {
        int row = m0 + wm + i*16 + (lane >> 4)*4 + r;
        float v = acc[i][j][r] + bias;
        float g = 0.5f * v * (1.0f + erff(v * 0.70710678118654752f));  // exact gelu
        H[(size_t)row*DFF + col] = f2bf(g);
      }
    }
  }
}

// ---- K9: GEMM2  out[token] = h @ w2 + b2, scatter f32, masked to count ----
__global__ __launch_bounds__(256) void ffn2_gemm(const u16* __restrict__ h,
    const u16* __restrict__ w2t, const float* __restrict__ b2,
    const int* __restrict__ offs, const int* __restrict__ pcnt,
    const int* __restrict__ counts, const int* __restrict__ lists,
    float* __restrict__ out) {
  const int BPE = 26*8;
  int bid = blockIdx.x;
  int e = bid / BPE, rem = bid % BPE;
  int mt = rem >> 3, nt = rem & 7;
  if (mt*128 >= pcnt[e]) return;
  int cnt = counts[e];
  const u16* A = h + (size_t)offs[e] * DFF;              // [rows][4096]
  const u16* B = w2t + (size_t)e * DMODEL * DFF;         // [1024][4096] = B^T
  __shared__ __align__(16) u16 As[128*32];
  __shared__ __align__(16) u16 Bs[128*32];
  int tid = threadIdx.x, lane = tid & 63, w = tid >> 6;
  int m0 = mt*128, n0 = nt*128;
  int wm = (w & 1)*64, wn = (w >> 1)*64;
  int fr = lane & 15, fkb = (lane >> 4)*8;
  f32x4 acc[4][4] = {};
  for (int kt = 0; kt < DFF; kt += 32) {
    __syncthreads();
#pragma unroll
    for (int i = 0; i < 2; ++i) {
      int slot = i*256 + tid;
      int row = slot >> 2, kc = slot & 3;
      async_cp16(A + (size_t)(m0+row)*DFF + kt + kc*8, As + (size_t)(i*256 + w*64)*8);
      async_cp16(B + (size_t)(n0+row)*DFF + kt + kc*8, Bs + (size_t)(i*256 + w*64)*8);
    }
    __syncthreads();
    bf16x8 af[4], bf[4];
#pragma unroll
    for (int i = 0; i < 4; ++i) af[i] = *(const bf16x8*)(As + (wm + i*16 + fr)*32 + fkb);
#pragma unroll
    for (int j = 0; j < 4; ++j) bf[j] = *(const bf16x8*)(Bs + (wn + j*16 + fr)*32 + fkb);
#pragma unroll
    for (int i = 0; i < 4; ++i)
#pragma unroll
      for (int j = 0; j < 4; ++j)
        acc[i][j] = __builtin_amdgcn_mfma_f32_16x16x32_bf16(af[i], bf[j], acc[i][j], 0, 0, 0);
  }
  const float* b2e = b2 + e*DMODEL;
  const int* liste = lists + e*CAP_PAD;
#pragma unroll
  for (int j = 0; j < 4; ++j) {
    int col = n0 + wn + j*16 + (lane & 15);
    float bias = b2e[col];
#pragma unroll
    for (int i = 0; i < 4; ++i) {
#pragma unroll
      for (int r = 0; r < 4; ++r) {
        int row = m0 + wm + i*16 + (lane >> 4)*4 + r;
        if (row < cnt) {
          int t = liste[row];
          out[(size_t)t*DMODEL + col] = acc[i][j][r] + bias;
        }
      }
    }
  }
}

extern "C" void kernel_launch(void* const* d_in, const int* in_sizes, int n_in,
                              void* d_out, int out_size, void* d_ws, size_t ws_size,
                              hipStream_t stream) {
  const float* x     = (const float*)d_in[0];
  const float* noise = (const float*)d_in[1];
  const float* rw    = (const float*)d_in[2];
  const float* rb    = (const float*)d_in[3];
  const float* w1    = (const float*)d_in[4];
  const float* b1    = (const float*)d_in[5];
  const float* w2    = (const float*)d_in[6];
  const float* b2    = (const float*)d_in[7];
  float* out = (float*)d_out;
  char* ws = (char*)d_ws;

  u16* w1t   = (u16*)(ws + W1T_OFF);
  u16* w2t   = (u16*)(ws + W2T_OFF);
  u16* xg    = (u16*)(ws + XG_OFF);
  u16* hbuf  = (u16*)(ws + H_OFF);
  int* topk  = (int*)(ws + TOPK_OFF);
  int* ccnt  = (int*)(ws + CCNT_OFF);
  int* cbase = (int*)(ws + CBASE_OFF);
  int* lists = (int*)(ws + LISTS_OFF);
  int* cnts  = (int*)(ws + CNT_OFF);
  int* offs  = (int*)(ws + OFFS_OFF);
  int* pcnt  = (int*)(ws + PCNT_OFF);

  // unassigned tokens must be zero; counts must start at zero
  hipMemsetAsync(d_out, 0, (size_t)T_TOK * DMODEL * sizeof(float), stream);
  hipMemsetAsync(cnts, 0, NEXP * sizeof(int), stream);

  transpose_cvt<<<NEXP*(DMODEL/32)*(DFF/32), 256, 0, stream>>>(w1, w1t, DMODEL, DFF);
  transpose_cvt<<<NEXP*(DFF/32)*(DMODEL/32), 256, 0, stream>>>(w2, w2t, DFF, DMODEL);
  router_topk<<<T_TOK/4, 256, 0, stream>>>(x, rw, rb, noise, topk);
  chunk_count<<<128, 128, 0, stream>>>(topk, ccnt);
  chunk_prefix<<<1, 64, 0, stream>>>(ccnt, cbase);
  assign_compact<<<128, 128, 0, stream>>>(topk, cbase, cnts, lists);
  calc_offsets<<<1, 64, 0, stream>>>(cnts, offs, pcnt);
  gather_x<<<NEXP*CAP_PAD, 128, 0, stream>>>(x, lists, cnts, offs, pcnt, xg);
  ffn1_gemm<<<NEXP*26*32, 256, 0, stream>>>(xg, w1t, b1, offs, pcnt, hbuf);
  ffn2_gemm<<<NEXP*26*8, 256, 0, stream>>>(hbuf, w2t, b2, offs, pcnt, cnts, lists, out);
}